// Round 5
// baseline (163.306 us; speedup 1.0000x reference)
//
#include <hip/hip_runtime.h>

#define B_ 8
#define N_ 4096
#define F_ 512

typedef __attribute__((ext_vector_type(8))) short bf16x8;
typedef __attribute__((ext_vector_type(4))) float f32x4;

// S (512 x 64) = [left | right | left_local | right_local], each [512][16] row-major.
__device__ __forceinline__ float Sval(const float* l, const float* r,
                                      const float* ll, const float* rl,
                                      int h, int e) {
    const int m = e >> 4, c = e & 15;
    const float* p = (m == 0) ? l : (m == 1) ? r : (m == 2) ? ll : rl;
    return p[h * 16 + c];
}

__device__ __forceinline__ float qval(const float* coeff, const float* coeff_l,
                                      int b, int j) {
    if (j < 16) return 1.f;
    if (j < 32) return coeff[b * 16 + (j - 16)];
    if (j < 48) return 1.f;
    return coeff_l[b * 16 + (j - 48)];
}

__device__ __forceinline__ float lane_bcast(float v, int lane) {
    return __int_as_float(__builtin_amdgcn_readlane(__float_as_int(v), lane));
}

__device__ __forceinline__ unsigned short bf16_rn(float x) {
    unsigned u = __float_as_uint(x);
    unsigned r = u + 0x7FFFu + ((u >> 16) & 1u);
    return (unsigned short)(r >> 16);
}

// split x ~= hi + lo, both bf16 (error ~2^-17 |x|)
__device__ __forceinline__ void bf16_split(float x, short& hi, short& lo) {
    const unsigned short h = bf16_rn(x);
    const float hf = __uint_as_float(((unsigned)h) << 16);
    const unsigned short s = bf16_rn(x - hf);
    hi = (short)h; lo = (short)s;
}

// GS = S^T S  (64x64). One block per row i.
__global__ __launch_bounds__(256) void k_gram(const float* l, const float* r,
                                              const float* ll, const float* rl,
                                              float* GS) {
    __shared__ float red[4][64];
    const int i = blockIdx.x;
    const int t = threadIdx.x;
    const int j = t & 63, seg = t >> 6;
    float acc = 0.f;
    const int h0 = seg * 128;
    for (int h = h0; h < h0 + 128; ++h)
        acc += Sval(l, r, ll, rl, h, i) * Sval(l, r, ll, rl, h, j);
    red[seg][j] = acc;
    __syncthreads();
    if (t < 64) GS[i * 64 + t] = red[0][t] + red[1][t] + red[2][t] + red[3][t];
}

// Sb = bf16 hi/lo split of S [512][64] (h-major, e contiguous).
__global__ __launch_bounds__(256) void k_sbf(const float* l, const float* r,
                                             const float* ll, const float* rl,
                                             unsigned short* Sbh, unsigned short* Sbl) {
    const int idx = blockIdx.x * 256 + threadIdx.x;  // 0..32767
    const int h = idx >> 6, e = idx & 63;
    const float v = Sval(l, r, ll, rl, h, e);
    short hh, ss;
    bf16_split(v, hh, ss);
    Sbh[idx] = (unsigned short)hh;
    Sbl[idx] = (unsigned short)ss;
}

// Build CP (64x64) and M = I - 0.5 CQ^T GS CP -> Mws, CPws. 8 blocks.
__global__ __launch_bounds__(256) void k_build_pre(const float* coeff, const float* gate,
                                                   const float* coeff_l, const float* gate_l,
                                                   const float* comm, const float* GS,
                                                   float* Mws, float* CPws) {
    __shared__ float GST[4096];
    __shared__ float CPs[4096];
    __shared__ float ABs[2048];
    __shared__ float u1s[32], u2s[32];

    const int b = blockIdx.x, t = threadIdx.x;
    const int tx = t & 15, ty = t >> 4;
    const float g = gate[b], gl = gate_l[b];
    const float cs = comm[b] / 12.0f;

    if (t < 32) {
        u1s[t] = (t < 16) ? g * coeff[b * 16 + t] : -g;
        u2s[t] = (t < 16) ? gl * coeff_l[b * 16 + t] : -gl;
    }
    for (int idx = t; idx < 4096; idx += 256) {
        const int i = idx & 63, e = idx >> 6;
        GST[idx] = -0.5f * qval(coeff, coeff_l, b, i) * GS[(i ^ 16) * 64 + e];
    }
    __syncthreads();

    for (int idx = t; idx < 2048; idx += 256) {
        const int which = idx >> 10;
        const int i = (idx >> 5) & 31, j = idx & 31;
        float val;
        if (which == 0) {
            const int v2i = (i < 16) ? 48 + i : 16 + i;
            const float v2sc = (i < 16) ? 1.f : coeff_l[b * 16 + (i - 16)];
            val = v2sc * u1s[j] * GS[v2i * 64 + j];
        } else {
            const int v1i = (i < 16) ? 16 + i : i - 16;
            const float v1sc = (i < 16) ? 1.f : coeff[b * 16 + (i - 16)];
            val = v1sc * u2s[j] * GS[v1i * 64 + 32 + j];
        }
        ABs[idx] = val;
    }
    __syncthreads();

    for (int idx = t; idx < 4096; idx += 256) {
        const int e = idx >> 6, j = idx & 63;
        float val = 0.f;
        if (j < 32) {
            if (e == j) val += 0.5f * u1s[j];
            if (e >= 32) val += cs * u2s[e - 32] * ABs[(e - 32) * 32 + j];
        } else {
            const int jp = j - 32;
            if (e == 32 + jp) val += 0.5f * u2s[jp];
            if (e < 32) val -= cs * u1s[e] * ABs[1024 + e * 32 + jp];
        }
        CPs[idx] = val;
        CPws[b * 4096 + idx] = val;
    }
    __syncthreads();

    {
        const int i0 = ty * 4, m0 = tx * 4;
        float acc[4][4];
#pragma unroll
        for (int i = 0; i < 4; ++i)
#pragma unroll
            for (int j = 0; j < 4; ++j) acc[i][j] = 0.f;
        for (int e = 0; e < 64; ++e) {
            const float4 av = *reinterpret_cast<const float4*>(&GST[e * 64 + i0]);
            const float4 bv = *reinterpret_cast<const float4*>(&CPs[e * 64 + m0]);
            const float a[4] = {av.x, av.y, av.z, av.w};
            const float bb[4] = {bv.x, bv.y, bv.z, bv.w};
#pragma unroll
            for (int i = 0; i < 4; ++i)
#pragma unroll
                for (int j = 0; j < 4; ++j) acc[i][j] += a[i] * bb[j];
        }
#pragma unroll
        for (int i = 0; i < 4; ++i) {
            float4 o;
            o.x = acc[i][0] + (((i0 + i) == (m0 + 0)) ? 1.f : 0.f);
            o.y = acc[i][1] + (((i0 + i) == (m0 + 1)) ? 1.f : 0.f);
            o.z = acc[i][2] + (((i0 + i) == (m0 + 2)) ? 1.f : 0.f);
            o.w = acc[i][3] + (((i0 + i) == (m0 + 3)) ? 1.f : 0.f);
            *reinterpret_cast<float4*>(&Mws[b * 4096 + (i0 + i) * 64 + m0]) = o;
        }
    }
}

// ---- k_inv: single-wave register Gauss-Jordan, macro-forced full unroll ----
#define DO64(M, K) \
    M(0, K) M(1, K) M(2, K) M(3, K) M(4, K) M(5, K) M(6, K) M(7, K) \
    M(8, K) M(9, K) M(10, K) M(11, K) M(12, K) M(13, K) M(14, K) M(15, K) \
    M(16, K) M(17, K) M(18, K) M(19, K) M(20, K) M(21, K) M(22, K) M(23, K) \
    M(24, K) M(25, K) M(26, K) M(27, K) M(28, K) M(29, K) M(30, K) M(31, K) \
    M(32, K) M(33, K) M(34, K) M(35, K) M(36, K) M(37, K) M(38, K) M(39, K) \
    M(40, K) M(41, K) M(42, K) M(43, K) M(44, K) M(45, K) M(46, K) M(47, K) \
    M(48, K) M(49, K) M(50, K) M(51, K) M(52, K) M(53, K) M(54, K) M(55, K) \
    M(56, K) M(57, K) M(58, K) M(59, K) M(60, K) M(61, K) M(62, K) M(63, K)

#define GJ_LOAD(RR, K) a[RR] = Mws[base + (RR)*64 + t];
#define GJ_STORE(RR, K) Kws[base + (RR)*64 + t] = a[RR];
#define GJ_UPD(RR, K) \
    if ((RR) != (K)) { \
        const float f = lane_bcast(a[RR], (K)); \
        a[RR] = ((t == (K)) ? 0.f : a[RR]) - f * a[K]; \
    }
#define GJ_STEP(K) { \
    const float dk = lane_bcast(a[K], (K)); \
    const float pinv = 1.0f / dk; \
    a[K] = (t == (K)) ? pinv : a[K] * pinv; \
    DO64(GJ_UPD, K) \
}

__global__ __launch_bounds__(64, 1) void k_inv(const float* Mws, float* Kws) {
    const int b = blockIdx.x, t = threadIdx.x;  // lane t owns column t
    const int base = b * 4096;
    float a[64];
    DO64(GJ_LOAD, 0)
    GJ_STEP(0) GJ_STEP(1) GJ_STEP(2) GJ_STEP(3)
    GJ_STEP(4) GJ_STEP(5) GJ_STEP(6) GJ_STEP(7)
    GJ_STEP(8) GJ_STEP(9) GJ_STEP(10) GJ_STEP(11)
    GJ_STEP(12) GJ_STEP(13) GJ_STEP(14) GJ_STEP(15)
    GJ_STEP(16) GJ_STEP(17) GJ_STEP(18) GJ_STEP(19)
    GJ_STEP(20) GJ_STEP(21) GJ_STEP(22) GJ_STEP(23)
    GJ_STEP(24) GJ_STEP(25) GJ_STEP(26) GJ_STEP(27)
    GJ_STEP(28) GJ_STEP(29) GJ_STEP(30) GJ_STEP(31)
    GJ_STEP(32) GJ_STEP(33) GJ_STEP(34) GJ_STEP(35)
    GJ_STEP(36) GJ_STEP(37) GJ_STEP(38) GJ_STEP(39)
    GJ_STEP(40) GJ_STEP(41) GJ_STEP(42) GJ_STEP(43)
    GJ_STEP(44) GJ_STEP(45) GJ_STEP(46) GJ_STEP(47)
    GJ_STEP(48) GJ_STEP(49) GJ_STEP(50) GJ_STEP(51)
    GJ_STEP(52) GJ_STEP(53) GJ_STEP(54) GJ_STEP(55)
    GJ_STEP(56) GJ_STEP(57) GJ_STEP(58) GJ_STEP(59)
    GJ_STEP(60) GJ_STEP(61) GJ_STEP(62) GJ_STEP(63)
    DO64(GJ_STORE, 0)
}

// Newton refinement + E: Td = CP*K, Ta = M*K, T1 = 2Td - Td*Ta,
// E[e][f] = q(f^16) * T1[e][f^16]. 8 blocks.
__global__ __launch_bounds__(256) void k_build_post(const float* coeff, const float* coeff_l,
                                                    const float* Mws, const float* CPws,
                                                    const float* Kws, float* Eout) {
    __shared__ float Ms[4096], CPs[4096], Ks[4096], Tds[4096], Tas[4096];
    const int b = blockIdx.x, t = threadIdx.x;
    const int tx = t & 15, ty = t >> 4;

    for (int idx = t; idx < 4096; idx += 256) {
        Ms[idx] = Mws[b * 4096 + idx];
        CPs[idx] = CPws[b * 4096 + idx];
        Ks[idx] = Kws[b * 4096 + idx];
    }
    __syncthreads();

    {
        const int i0 = ty * 4, j0 = tx * 4;
        float accd[4][4], acca[4][4];
#pragma unroll
        for (int i = 0; i < 4; ++i)
#pragma unroll
            for (int j = 0; j < 4; ++j) { accd[i][j] = 0.f; acca[i][j] = 0.f; }
        for (int q = 0; q < 64; ++q) {
            const float4 bv = *reinterpret_cast<const float4*>(&Ks[q * 64 + j0]);
            const float bb[4] = {bv.x, bv.y, bv.z, bv.w};
            float ad[4], aa[4];
#pragma unroll
            for (int i = 0; i < 4; ++i) {
                ad[i] = CPs[(i0 + i) * 64 + q];
                aa[i] = Ms[(i0 + i) * 64 + q];
            }
#pragma unroll
            for (int i = 0; i < 4; ++i)
#pragma unroll
                for (int j = 0; j < 4; ++j) {
                    accd[i][j] += ad[i] * bb[j];
                    acca[i][j] += aa[i] * bb[j];
                }
        }
#pragma unroll
        for (int i = 0; i < 4; ++i)
#pragma unroll
            for (int j = 0; j < 4; ++j) {
                Tds[(i0 + i) * 64 + j0 + j] = accd[i][j];
                Tas[(i0 + i) * 64 + j0 + j] = acca[i][j];
            }
    }
    __syncthreads();

    {
        const int e0 = ty * 4, c0 = tx * 4;
        float acc[4][4];
#pragma unroll
        for (int i = 0; i < 4; ++i)
#pragma unroll
            for (int j = 0; j < 4; ++j) acc[i][j] = 0.f;
        for (int q = 0; q < 64; ++q) {
            const float4 bv = *reinterpret_cast<const float4*>(&Tas[q * 64 + c0]);
            const float bb[4] = {bv.x, bv.y, bv.z, bv.w};
            float a[4];
#pragma unroll
            for (int i = 0; i < 4; ++i) a[i] = Tds[(e0 + i) * 64 + q];
#pragma unroll
            for (int i = 0; i < 4; ++i)
#pragma unroll
                for (int j = 0; j < 4; ++j) acc[i][j] += a[i] * bb[j];
        }
        float qv[4];
#pragma unroll
        for (int j = 0; j < 4; ++j) qv[j] = qval(coeff, coeff_l, b, c0 + j);
#pragma unroll
        for (int i = 0; i < 4; ++i) {
            float4 o;
            o.x = qv[0] * (2.f * Tds[(e0 + i) * 64 + c0 + 0] - acc[i][0]);
            o.y = qv[1] * (2.f * Tds[(e0 + i) * 64 + c0 + 1] - acc[i][1]);
            o.z = qv[2] * (2.f * Tds[(e0 + i) * 64 + c0 + 2] - acc[i][2]);
            o.w = qv[3] * (2.f * Tds[(e0 + i) * 64 + c0 + 3] - acc[i][3]);
            *reinterpret_cast<float4*>(&Eout[b * 4096 + (e0 + i) * 64 + (c0 ^ 16)]) = o;
        }
    }
}

// SE_b = S * E_b (512 x 64), written as bf16 hi/lo TRANSPOSED: SEt[n][k] [64][512].
// grid (hc=8, b=8)
__global__ __launch_bounds__(256) void k_se(const float* l, const float* r,
                                            const float* ll, const float* rl,
                                            const float* Ein,
                                            unsigned short* SEth, unsigned short* SEtl) {
    __shared__ float Es[4096];
    const int b = blockIdx.y, hc = blockIdx.x, t = threadIdx.x;
    for (int idx = t; idx < 4096; idx += 256) Es[idx] = Ein[b * 4096 + idx];
    __syncthreads();
    const int h = hc * 64 + (t >> 2);
    const int mg = (t & 3) * 16;
    float acc[16];
#pragma unroll
    for (int q = 0; q < 16; ++q) acc[q] = 0.f;
#pragma unroll 4
    for (int e = 0; e < 64; ++e) {
        const float s = Sval(l, r, ll, rl, h, e);
        const float* Er = Es + e * 64 + mg;
#pragma unroll
        for (int q = 0; q < 16; ++q) acc[q] += s * Er[q];
    }
    unsigned short* oh = SEth + (size_t)b * (64 * 512);
    unsigned short* ol = SEtl + (size_t)b * (64 * 512);
#pragma unroll
    for (int q = 0; q < 16; ++q) {
        short hh, ss;
        bf16_split(acc[q], hh, ss);
        oh[(mg + q) * 512 + h] = (unsigned short)hh;
        ol[(mg + q) * 512 + h] = (unsigned short)ss;
    }
}

// out = x + ((x * SE_b) * S^T) via split-bf16 MFMA.
// grid (row-tile=64, b=8), 256 thr = 4 waves, 16 rows/wave.
// MFMA 16x16x32 layouts: A: [m=l&15][k=(l>>4)*8+i]; B: [k=(l>>4)*8+i][n=l&15];
// C/D: [m=(l>>4)*4+r][n=l&15]  (m89-verified).
__global__ __launch_bounds__(256) void k_mix(const float* x,
                                             const unsigned short* SEth,
                                             const unsigned short* SEtl,
                                             const unsigned short* Sbh,
                                             const unsigned short* Sbl,
                                             float* out) {
    __shared__ float Zs[64 * 68];
    const int b = blockIdx.y;
    const int r0 = blockIdx.x * 64;
    const int t = threadIdx.x;
    const int w = t >> 6;
    const int l = t & 63;
    const int lm = l & 15;
    const int lk = (l >> 4) * 8;
    const float* xb = x + (size_t)b * N_ * F_;
    float* outb = out + (size_t)b * N_ * F_;
    const unsigned short* seh = SEth + (size_t)b * (64 * 512);
    const unsigned short* sel = SEtl + (size_t)b * (64 * 512);

    // ---- phase 1: Z[64][64] = X_tile * SE ----
    f32x4 acc0 = {0.f, 0.f, 0.f, 0.f}, acc1 = {0.f, 0.f, 0.f, 0.f};
    f32x4 acc2 = {0.f, 0.f, 0.f, 0.f}, acc3 = {0.f, 0.f, 0.f, 0.f};
    const int arow = r0 + 16 * w + lm;
    for (int kk = 0; kk < 16; ++kk) {
        const int k0 = kk * 32 + lk;
        const float4 xa = *reinterpret_cast<const float4*>(xb + (size_t)arow * F_ + k0);
        const float4 xc = *reinterpret_cast<const float4*>(xb + (size_t)arow * F_ + k0 + 4);
        const float xs[8] = {xa.x, xa.y, xa.z, xa.w, xc.x, xc.y, xc.z, xc.w};
        bf16x8 ah, al;
#pragma unroll
        for (int i = 0; i < 8; ++i) {
            short hh, ss;
            bf16_split(xs[i], hh, ss);
            ah[i] = hh; al[i] = ss;
        }
#pragma unroll
        for (int j = 0; j < 4; ++j) {
            const int n = 16 * j + lm;
            const bf16x8 bh = *reinterpret_cast<const bf16x8*>(seh + n * 512 + k0);
            const bf16x8 bl = *reinterpret_cast<const bf16x8*>(sel + n * 512 + k0);
            f32x4& acc = (j == 0) ? acc0 : (j == 1) ? acc1 : (j == 2) ? acc2 : acc3;
            acc = __builtin_amdgcn_mfma_f32_16x16x32_bf16(ah, bh, acc, 0, 0, 0);
            acc = __builtin_amdgcn_mfma_f32_16x16x32_bf16(al, bh, acc, 0, 0, 0);
            acc = __builtin_amdgcn_mfma_f32_16x16x32_bf16(ah, bl, acc, 0, 0, 0);
        }
    }
    // spill Z to LDS in [row][col] (pad 68: 2-way conflicts only)
#pragma unroll
    for (int r = 0; r < 4; ++r) {
        const int zr = (16 * w + (l >> 4) * 4 + r) * 68;
        Zs[zr + lm] = acc0[r];
        Zs[zr + 16 + lm] = acc1[r];
        Zs[zr + 32 + lm] = acc2[r];
        Zs[zr + 48 + lm] = acc3[r];
    }
    __syncthreads();

    // ---- phase 2: out = X + Z * S^T ----
    bf16x8 zh0, zl0, zh1, zl1;
    {
        const float* zrow = &Zs[(16 * w + lm) * 68];
#pragma unroll
        for (int i = 0; i < 8; ++i) {
            short hh, ss;
            bf16_split(zrow[lk + i], hh, ss);
            zh0[i] = hh; zl0[i] = ss;
            bf16_split(zrow[32 + lk + i], hh, ss);
            zh1[i] = hh; zl1[i] = ss;
        }
    }
    const int orow0 = r0 + 16 * w + (l >> 4) * 4;
    for (int j2 = 0; j2 < 32; ++j2) {
        const int h0 = 16 * j2 + lm;
        f32x4 c;
#pragma unroll
        for (int r = 0; r < 4; ++r) c[r] = xb[(size_t)(orow0 + r) * F_ + h0];
        {
            const bf16x8 bh = *reinterpret_cast<const bf16x8*>(Sbh + h0 * 64 + lk);
            const bf16x8 bl = *reinterpret_cast<const bf16x8*>(Sbl + h0 * 64 + lk);
            c = __builtin_amdgcn_mfma_f32_16x16x32_bf16(zh0, bh, c, 0, 0, 0);
            c = __builtin_amdgcn_mfma_f32_16x16x32_bf16(zl0, bh, c, 0, 0, 0);
            c = __builtin_amdgcn_mfma_f32_16x16x32_bf16(zh0, bl, c, 0, 0, 0);
        }
        {
            const bf16x8 bh = *reinterpret_cast<const bf16x8*>(Sbh + h0 * 64 + 32 + lk);
            const bf16x8 bl = *reinterpret_cast<const bf16x8*>(Sbl + h0 * 64 + 32 + lk);
            c = __builtin_amdgcn_mfma_f32_16x16x32_bf16(zh1, bh, c, 0, 0, 0);
            c = __builtin_amdgcn_mfma_f32_16x16x32_bf16(zl1, bh, c, 0, 0, 0);
            c = __builtin_amdgcn_mfma_f32_16x16x32_bf16(zh1, bl, c, 0, 0, 0);
        }
#pragma unroll
        for (int r = 0; r < 4; ++r) outb[(size_t)(orow0 + r) * F_ + h0] = c[r];
    }
}

extern "C" void kernel_launch(void* const* d_in, const int* in_sizes, int n_in,
                              void* d_out, int out_size, void* d_ws, size_t ws_size,
                              hipStream_t stream) {
    (void)in_sizes; (void)n_in; (void)out_size; (void)ws_size;
    const float* x       = (const float*)d_in[0];
    const float* coeff   = (const float*)d_in[1];
    const float* gate    = (const float*)d_in[2];
    const float* coeff_l = (const float*)d_in[3];
    const float* gate_l  = (const float*)d_in[4];
    const float* comm    = (const float*)d_in[5];
    const float* l       = (const float*)d_in[6];
    const float* r       = (const float*)d_in[7];
    const float* ll      = (const float*)d_in[8];
    const float* rl      = (const float*)d_in[9];

    char* wsb = (char*)d_ws;
    float* GS   = (float*)(wsb);                 // 4096 f          @0
    float* E    = (float*)(wsb + 16384);         // 8*4096 f        @16K
    float* Mws  = (float*)(wsb + 147456);        // 8*4096 f        @144K
    float* CPws = (float*)(wsb + 278528);        // 8*4096 f        @272K
    float* Kws  = (float*)(wsb + 409600);        // 8*4096 f        @400K
    unsigned short* SEth = (unsigned short*)(wsb + 540672);   // 8*64*512 u16 @528K
    unsigned short* SEtl = (unsigned short*)(wsb + 1064960);  // @1040K
    unsigned short* Sbh  = (unsigned short*)(wsb + 1589248);  // 512*64 u16   @1552K
    unsigned short* Sbl  = (unsigned short*)(wsb + 1654784);  // @1616K (ends 1680K)
    float* out = (float*)d_out;

    k_sbf<<<dim3(128), dim3(256), 0, stream>>>(l, r, ll, rl, Sbh, Sbl);
    k_gram<<<dim3(64), dim3(256), 0, stream>>>(l, r, ll, rl, GS);
    k_build_pre<<<dim3(8), dim3(256), 0, stream>>>(coeff, gate, coeff_l, gate_l, comm, GS,
                                                   Mws, CPws);
    k_inv<<<dim3(8), dim3(64), 0, stream>>>(Mws, Kws);
    k_build_post<<<dim3(8), dim3(256), 0, stream>>>(coeff, coeff_l, Mws, CPws, Kws, E);
    k_se<<<dim3(8, 8), dim3(256), 0, stream>>>(l, r, ll, rl, E, SEth, SEtl);
    k_mix<<<dim3(64, 8), dim3(256), 0, stream>>>(x, SEth, SEtl, Sbh, Sbl, out);
}

// Round 6
// 154.916 us; speedup vs baseline: 1.0542x; 1.0542x over previous
//
#include <hip/hip_runtime.h>

#define B_ 8
#define N_ 4096
#define F_ 512

typedef __attribute__((ext_vector_type(8))) short bf16x8;
typedef __attribute__((ext_vector_type(4))) float f32x4;

// S (512 x 64) = [left | right | left_local | right_local], each [512][16] row-major.
__device__ __forceinline__ float Sval(const float* l, const float* r,
                                      const float* ll, const float* rl,
                                      int h, int e) {
    const int m = e >> 4, c = e & 15;
    const float* p = (m == 0) ? l : (m == 1) ? r : (m == 2) ? ll : rl;
    return p[h * 16 + c];
}

__device__ __forceinline__ float qval(const float* coeff, const float* coeff_l,
                                      int b, int j) {
    if (j < 16) return 1.f;
    if (j < 32) return coeff[b * 16 + (j - 16)];
    if (j < 48) return 1.f;
    return coeff_l[b * 16 + (j - 48)];
}

__device__ __forceinline__ float lane_bcast(float v, int lane) {
    return __int_as_float(__builtin_amdgcn_readlane(__float_as_int(v), lane));
}

__device__ __forceinline__ unsigned short bf16_rn(float x) {
    unsigned u = __float_as_uint(x);
    unsigned r = u + 0x7FFFu + ((u >> 16) & 1u);
    return (unsigned short)(r >> 16);
}

// split x ~= hi + lo, both bf16 (error ~2^-17 |x|)
__device__ __forceinline__ void bf16_split(float x, short& hi, short& lo) {
    const unsigned short h = bf16_rn(x);
    const float hf = __uint_as_float(((unsigned)h) << 16);
    const unsigned short s = bf16_rn(x - hf);
    hi = (short)h; lo = (short)s;
}

// ---- k_prep: GS = S^T S (row i per block) + bf16 hi/lo split of S. grid 64.
__global__ __launch_bounds__(256) void k_prep(const float* l, const float* r,
                                              const float* ll, const float* rl,
                                              float* GS,
                                              unsigned short* Sbh, unsigned short* Sbl) {
    __shared__ float red[4][64];
    const int i = blockIdx.x;
    const int t = threadIdx.x;
    const int j = t & 63, seg = t >> 6;

    // Sb slice: 512 elems per block, 2 per thread
    {
        const int idx0 = i * 512 + t;
        const int idx1 = idx0 + 256;
        short hh, ss;
        bf16_split(Sval(l, r, ll, rl, idx0 >> 6, idx0 & 63), hh, ss);
        Sbh[idx0] = (unsigned short)hh; Sbl[idx0] = (unsigned short)ss;
        bf16_split(Sval(l, r, ll, rl, idx1 >> 6, idx1 & 63), hh, ss);
        Sbh[idx1] = (unsigned short)hh; Sbl[idx1] = (unsigned short)ss;
    }

    float acc = 0.f;
    const int h0 = seg * 128;
    for (int h = h0; h < h0 + 128; ++h)
        acc += Sval(l, r, ll, rl, h, i) * Sval(l, r, ll, rl, h, j);
    red[seg][j] = acc;
    __syncthreads();
    if (t < 64) GS[i * 64 + t] = red[0][t] + red[1][t] + red[2][t] + red[3][t];
}

// ---- macro-unrolled register Gauss-Jordan (literal indices only) ----
#define DO64(M, K) \
    M(0, K) M(1, K) M(2, K) M(3, K) M(4, K) M(5, K) M(6, K) M(7, K) \
    M(8, K) M(9, K) M(10, K) M(11, K) M(12, K) M(13, K) M(14, K) M(15, K) \
    M(16, K) M(17, K) M(18, K) M(19, K) M(20, K) M(21, K) M(22, K) M(23, K) \
    M(24, K) M(25, K) M(26, K) M(27, K) M(28, K) M(29, K) M(30, K) M(31, K) \
    M(32, K) M(33, K) M(34, K) M(35, K) M(36, K) M(37, K) M(38, K) M(39, K) \
    M(40, K) M(41, K) M(42, K) M(43, K) M(44, K) M(45, K) M(46, K) M(47, K) \
    M(48, K) M(49, K) M(50, K) M(51, K) M(52, K) M(53, K) M(54, K) M(55, K) \
    M(56, K) M(57, K) M(58, K) M(59, K) M(60, K) M(61, K) M(62, K) M(63, K)

#define GJ_LOAD(RR, K) a[RR] = MsL[(RR) * 64 + t];
#define GJ_STORE(RR, K) KsL[(RR) * 64 + t] = a[RR];
#define GJ_UPD(RR, K) \
    if ((RR) != (K)) { \
        const float f = lane_bcast(a[RR], (K)); \
        a[RR] = ((t == (K)) ? 0.f : a[RR]) - f * a[K]; \
    }
#define GJ_STEP(K) { \
    const float dk = lane_bcast(a[K], (K)); \
    const float pinv = 1.0f / dk; \
    a[K] = (t == (K)) ? pinv : a[K] * pinv; \
    DO64(GJ_UPD, K) \
}

// ---- k_solve: per-batch build M,CP -> wave-0 register GJ -> Newton -> E.
// LDS regions (floats): R0 CPs [0,4096) | R1 GST [4096,8192) | R2 Ms [8192,12288)
// | R3 Ks [12288,16384). ABs overlays R2[0:2048); u1/u2 overlay R3[0:64).
__global__ __launch_bounds__(256, 1) void k_solve(const float* coeff, const float* gate,
                                                  const float* coeff_l, const float* gate_l,
                                                  const float* comm, const float* GS,
                                                  float* Eout) {
    __shared__ float smem[16384];
    float* CPs = smem;
    float* GST = smem + 4096;
    float* MsL = smem + 8192;
    float* KsL = smem + 12288;
    float* ABs = MsL;       // dead before M written
    float* u1s = KsL;       // 32, dead before K written
    float* u2s = KsL + 32;  // 32

    const int b = blockIdx.x, t = threadIdx.x;
    const int tx = t & 15, ty = t >> 4;
    const float g = gate[b], gl = gate_l[b];
    const float cs = comm[b] / 12.0f;

    // (a) u1/u2 + GST[e*64+i] = -0.5*q(i)*GS[(i^16)][e]
    if (t < 32) {
        u1s[t] = (t < 16) ? g * coeff[b * 16 + t] : -g;
        u2s[t] = (t < 16) ? gl * coeff_l[b * 16 + t] : -gl;
    }
    for (int idx = t; idx < 4096; idx += 256) {
        const int i = idx & 63, e = idx >> 6;
        GST[idx] = -0.5f * qval(coeff, coeff_l, b, i) * GS[(i ^ 16) * 64 + e];
    }
    __syncthreads();

    // (b) AB: A [32][32] at 0, B at 1024
    for (int idx = t; idx < 2048; idx += 256) {
        const int which = idx >> 10;
        const int i = (idx >> 5) & 31, j = idx & 31;
        float val;
        if (which == 0) {
            const int v2i = (i < 16) ? 48 + i : 16 + i;
            const float v2sc = (i < 16) ? 1.f : coeff_l[b * 16 + (i - 16)];
            val = v2sc * u1s[j] * GS[v2i * 64 + j];
        } else {
            const int v1i = (i < 16) ? 16 + i : i - 16;
            const float v1sc = (i < 16) ? 1.f : coeff[b * 16 + (i - 16)];
            val = v1sc * u2s[j] * GS[v1i * 64 + 32 + j];
        }
        ABs[idx] = val;
    }
    __syncthreads();

    // (c) CP
    for (int idx = t; idx < 4096; idx += 256) {
        const int e = idx >> 6, j = idx & 63;
        float val = 0.f;
        if (j < 32) {
            if (e == j) val += 0.5f * u1s[j];
            if (e >= 32) val += cs * u2s[e - 32] * ABs[(e - 32) * 32 + j];
        } else {
            const int jp = j - 32;
            if (e == 32 + jp) val += 0.5f * u2s[jp];
            if (e < 32) val -= cs * u1s[e] * ABs[1024 + e * 32 + jp];
        }
        CPs[idx] = val;
    }
    __syncthreads();

    // (d) M[i][m] = d(i,m) + sum_e GST[e][i] * CP[e][m]  (ABs dead) -> MsL
    {
        const int i0 = ty * 4, m0 = tx * 4;
        float acc[4][4];
#pragma unroll
        for (int i = 0; i < 4; ++i)
#pragma unroll
            for (int j = 0; j < 4; ++j) acc[i][j] = 0.f;
        for (int e = 0; e < 64; ++e) {
            const float4 av = *reinterpret_cast<const float4*>(&GST[e * 64 + i0]);
            const float4 bv = *reinterpret_cast<const float4*>(&CPs[e * 64 + m0]);
            const float a[4] = {av.x, av.y, av.z, av.w};
            const float bb[4] = {bv.x, bv.y, bv.z, bv.w};
#pragma unroll
            for (int i = 0; i < 4; ++i)
#pragma unroll
                for (int j = 0; j < 4; ++j) acc[i][j] += a[i] * bb[j];
        }
        __syncthreads();  // ABs reads done everywhere before overwrite
#pragma unroll
        for (int i = 0; i < 4; ++i)
#pragma unroll
            for (int j = 0; j < 4; ++j)
                MsL[(i0 + i) * 64 + m0 + j] =
                    acc[i][j] + (((i0 + i) == (m0 + j)) ? 1.f : 0.f);
    }
    __syncthreads();

    // (e) wave-0 register GJ: lane t owns column t; K -> R3 (u1/u2 dead)
    if (t < 64) {
        float a[64];
        DO64(GJ_LOAD, 0)
        GJ_STEP(0) GJ_STEP(1) GJ_STEP(2) GJ_STEP(3)
        GJ_STEP(4) GJ_STEP(5) GJ_STEP(6) GJ_STEP(7)
        GJ_STEP(8) GJ_STEP(9) GJ_STEP(10) GJ_STEP(11)
        GJ_STEP(12) GJ_STEP(13) GJ_STEP(14) GJ_STEP(15)
        GJ_STEP(16) GJ_STEP(17) GJ_STEP(18) GJ_STEP(19)
        GJ_STEP(20) GJ_STEP(21) GJ_STEP(22) GJ_STEP(23)
        GJ_STEP(24) GJ_STEP(25) GJ_STEP(26) GJ_STEP(27)
        GJ_STEP(28) GJ_STEP(29) GJ_STEP(30) GJ_STEP(31)
        GJ_STEP(32) GJ_STEP(33) GJ_STEP(34) GJ_STEP(35)
        GJ_STEP(36) GJ_STEP(37) GJ_STEP(38) GJ_STEP(39)
        GJ_STEP(40) GJ_STEP(41) GJ_STEP(42) GJ_STEP(43)
        GJ_STEP(44) GJ_STEP(45) GJ_STEP(46) GJ_STEP(47)
        GJ_STEP(48) GJ_STEP(49) GJ_STEP(50) GJ_STEP(51)
        GJ_STEP(52) GJ_STEP(53) GJ_STEP(54) GJ_STEP(55)
        GJ_STEP(56) GJ_STEP(57) GJ_STEP(58) GJ_STEP(59)
        GJ_STEP(60) GJ_STEP(61) GJ_STEP(62) GJ_STEP(63)
        DO64(GJ_STORE, 0)
    }
    __syncthreads();

    // (f,g) Td = CP*K, Ta = M*K (regs) -> then Td->R1 (GST dead), Ta->R0 (CP dead)
    {
        const int i0 = ty * 4, j0 = tx * 4;
        float accd[4][4], acca[4][4];
#pragma unroll
        for (int i = 0; i < 4; ++i)
#pragma unroll
            for (int j = 0; j < 4; ++j) { accd[i][j] = 0.f; acca[i][j] = 0.f; }
        for (int q = 0; q < 64; ++q) {
            const float4 bv = *reinterpret_cast<const float4*>(&KsL[q * 64 + j0]);
            const float bb[4] = {bv.x, bv.y, bv.z, bv.w};
            float ad[4], aa[4];
#pragma unroll
            for (int i = 0; i < 4; ++i) {
                ad[i] = CPs[(i0 + i) * 64 + q];
                aa[i] = MsL[(i0 + i) * 64 + q];
            }
#pragma unroll
            for (int i = 0; i < 4; ++i)
#pragma unroll
                for (int j = 0; j < 4; ++j) {
                    accd[i][j] += ad[i] * bb[j];
                    acca[i][j] += aa[i] * bb[j];
                }
        }
        __syncthreads();  // everyone done reading CPs/GST
#pragma unroll
        for (int i = 0; i < 4; ++i)
#pragma unroll
            for (int j = 0; j < 4; ++j) {
                GST[(i0 + i) * 64 + j0 + j] = accd[i][j];  // Td
                CPs[(i0 + i) * 64 + j0 + j] = acca[i][j];  // Ta
            }
    }
    __syncthreads();

    // (h,i) T1 = 2*Td - Td*Ta ; E[e][(c0+j)^16... ] = q(c0+j)*T1[e][c0+j] -> global
    {
        const int e0 = ty * 4, c0 = tx * 4;
        float acc[4][4];
#pragma unroll
        for (int i = 0; i < 4; ++i)
#pragma unroll
            for (int j = 0; j < 4; ++j) acc[i][j] = 0.f;
        for (int q = 0; q < 64; ++q) {
            const float4 bv = *reinterpret_cast<const float4*>(&CPs[q * 64 + c0]);
            const float bb[4] = {bv.x, bv.y, bv.z, bv.w};
            float a[4];
#pragma unroll
            for (int i = 0; i < 4; ++i) a[i] = GST[(e0 + i) * 64 + q];
#pragma unroll
            for (int i = 0; i < 4; ++i)
#pragma unroll
                for (int j = 0; j < 4; ++j) acc[i][j] += a[i] * bb[j];
        }
        float qv[4];
#pragma unroll
        for (int j = 0; j < 4; ++j) qv[j] = qval(coeff, coeff_l, b, c0 + j);
#pragma unroll
        for (int i = 0; i < 4; ++i) {
            float4 o;
            o.x = qv[0] * (2.f * GST[(e0 + i) * 64 + c0 + 0] - acc[i][0]);
            o.y = qv[1] * (2.f * GST[(e0 + i) * 64 + c0 + 1] - acc[i][1]);
            o.z = qv[2] * (2.f * GST[(e0 + i) * 64 + c0 + 2] - acc[i][2]);
            o.w = qv[3] * (2.f * GST[(e0 + i) * 64 + c0 + 3] - acc[i][3]);
            *reinterpret_cast<float4*>(&Eout[b * 4096 + (e0 + i) * 64 + (c0 ^ 16)]) = o;
        }
    }
}

// SE_b = S * E_b (512 x 64), written as bf16 hi/lo TRANSPOSED: SEt[n][k] [64][512].
// grid (hc=8, b=8)
__global__ __launch_bounds__(256) void k_se(const float* l, const float* r,
                                            const float* ll, const float* rl,
                                            const float* Ein,
                                            unsigned short* SEth, unsigned short* SEtl) {
    __shared__ float Es[4096];
    const int b = blockIdx.y, hc = blockIdx.x, t = threadIdx.x;
    for (int idx = t; idx < 4096; idx += 256) Es[idx] = Ein[b * 4096 + idx];
    __syncthreads();
    const int h = hc * 64 + (t >> 2);
    const int mg = (t & 3) * 16;
    float acc[16];
#pragma unroll
    for (int q = 0; q < 16; ++q) acc[q] = 0.f;
#pragma unroll 4
    for (int e = 0; e < 64; ++e) {
        const float s = Sval(l, r, ll, rl, h, e);
        const float* Er = Es + e * 64 + mg;
#pragma unroll
        for (int q = 0; q < 16; ++q) acc[q] += s * Er[q];
    }
    unsigned short* oh = SEth + (size_t)b * (64 * 512);
    unsigned short* ol = SEtl + (size_t)b * (64 * 512);
#pragma unroll
    for (int q = 0; q < 16; ++q) {
        short hh, ss;
        bf16_split(acc[q], hh, ss);
        oh[(mg + q) * 512 + h] = (unsigned short)hh;
        ol[(mg + q) * 512 + h] = (unsigned short)ss;
    }
}

// out = x + ((x * SE_b) * S^T) via split-bf16 MFMA.
// grid (row-tile=32 -> 128, b=8) = 1024 blocks (4/CU), 256 thr = 4 waves.
// wave w: rw=w&1 (16-row half), cw=w>>1 (col half: ph1 32 Z-cols / ph2 256 out-cols).
// MFMA 16x16x32: A[m=l&15][k=(l>>4)*8+i]; B[k][n=l&15]; C[m=(l>>4)*4+r][n=l&15].
__global__ __launch_bounds__(256, 4) void k_mix(const float* x,
                                                const unsigned short* SEth,
                                                const unsigned short* SEtl,
                                                const unsigned short* Sbh,
                                                const unsigned short* Sbl,
                                                float* out) {
    __shared__ float Zs[32 * 68];
    const int b = blockIdx.y;
    const int r0 = blockIdx.x * 32;
    const int t = threadIdx.x;
    const int w = t >> 6;
    const int l = t & 63;
    const int lm = l & 15;
    const int lk = (l >> 4) * 8;
    const int rw = w & 1, cw = w >> 1;
    const float* xb = x + (size_t)b * N_ * F_;
    float* outb = out + (size_t)b * N_ * F_;
    const unsigned short* seh = SEth + (size_t)b * (64 * 512);
    const unsigned short* sel = SEtl + (size_t)b * (64 * 512);

    // ---- phase 1: Z[32][64] = X_tile * SE ; 3 independent chains per n-tile ----
    f32x4 ahh0 = {0.f, 0.f, 0.f, 0.f}, alh0 = ahh0, ahl0 = ahh0;
    f32x4 ahh1 = ahh0, alh1 = ahh0, ahl1 = ahh0;
    const int arow = r0 + 16 * rw + lm;
    const float* xrow = xb + (size_t)arow * F_;
    const int n0 = 32 * cw + lm;
#pragma unroll 2
    for (int kk = 0; kk < 16; ++kk) {
        const int k0 = kk * 32 + lk;
        const float4 xa = *reinterpret_cast<const float4*>(xrow + k0);
        const float4 xc = *reinterpret_cast<const float4*>(xrow + k0 + 4);
        const float xs[8] = {xa.x, xa.y, xa.z, xa.w, xc.x, xc.y, xc.z, xc.w};
        bf16x8 ah, al;
#pragma unroll
        for (int i = 0; i < 8; ++i) {
            short hh, ss;
            bf16_split(xs[i], hh, ss);
            ah[i] = hh; al[i] = ss;
        }
        const bf16x8 bh0 = *reinterpret_cast<const bf16x8*>(seh + n0 * 512 + k0);
        const bf16x8 bl0 = *reinterpret_cast<const bf16x8*>(sel + n0 * 512 + k0);
        const bf16x8 bh1 = *reinterpret_cast<const bf16x8*>(seh + (n0 + 16) * 512 + k0);
        const bf16x8 bl1 = *reinterpret_cast<const bf16x8*>(sel + (n0 + 16) * 512 + k0);
        ahh0 = __builtin_amdgcn_mfma_f32_16x16x32_bf16(ah, bh0, ahh0, 0, 0, 0);
        alh0 = __builtin_amdgcn_mfma_f32_16x16x32_bf16(al, bh0, alh0, 0, 0, 0);
        ahl0 = __builtin_amdgcn_mfma_f32_16x16x32_bf16(ah, bl0, ahl0, 0, 0, 0);
        ahh1 = __builtin_amdgcn_mfma_f32_16x16x32_bf16(ah, bh1, ahh1, 0, 0, 0);
        alh1 = __builtin_amdgcn_mfma_f32_16x16x32_bf16(al, bh1, alh1, 0, 0, 0);
        ahl1 = __builtin_amdgcn_mfma_f32_16x16x32_bf16(ah, bl1, ahl1, 0, 0, 0);
    }
#pragma unroll
    for (int r = 0; r < 4; ++r) {
        const int zr = (16 * rw + (l >> 4) * 4 + r) * 68 + 32 * cw;
        Zs[zr + lm] = ahh0[r] + alh0[r] + ahl0[r];
        Zs[zr + 16 + lm] = ahh1[r] + alh1[r] + ahl1[r];
    }
    __syncthreads();

    // ---- phase 2: out[32][512] = X + Z * S^T ; wave covers rows 16*rw, cols 256*cw ----
    bf16x8 zh0, zl0, zh1, zl1;
    {
        const float* zrow = &Zs[(16 * rw + lm) * 68];
#pragma unroll
        for (int i = 0; i < 8; ++i) {
            short hh, ss;
            bf16_split(zrow[lk + i], hh, ss);
            zh0[i] = hh; zl0[i] = ss;
            bf16_split(zrow[32 + lk + i], hh, ss);
            zh1[i] = hh; zl1[i] = ss;
        }
    }
    const int orow0 = r0 + 16 * rw + (l >> 4) * 4;
#pragma unroll 2
    for (int j2 = 0; j2 < 16; ++j2) {
        const int h0 = 256 * cw + 16 * j2 + lm;
        f32x4 ca = {0.f, 0.f, 0.f, 0.f};
        f32x4 cb;
#pragma unroll
        for (int r = 0; r < 4; ++r) cb[r] = xb[(size_t)(orow0 + r) * F_ + h0];
        const bf16x8 bh0 = *reinterpret_cast<const bf16x8*>(Sbh + h0 * 64 + lk);
        const bf16x8 bl0 = *reinterpret_cast<const bf16x8*>(Sbl + h0 * 64 + lk);
        const bf16x8 bh1 = *reinterpret_cast<const bf16x8*>(Sbh + h0 * 64 + 32 + lk);
        const bf16x8 bl1 = *reinterpret_cast<const bf16x8*>(Sbl + h0 * 64 + 32 + lk);
        ca = __builtin_amdgcn_mfma_f32_16x16x32_bf16(zh0, bh0, ca, 0, 0, 0);
        ca = __builtin_amdgcn_mfma_f32_16x16x32_bf16(zl0, bh0, ca, 0, 0, 0);
        ca = __builtin_amdgcn_mfma_f32_16x16x32_bf16(zh0, bl0, ca, 0, 0, 0);
        cb = __builtin_amdgcn_mfma_f32_16x16x32_bf16(zh1, bh1, cb, 0, 0, 0);
        cb = __builtin_amdgcn_mfma_f32_16x16x32_bf16(zl1, bh1, cb, 0, 0, 0);
        cb = __builtin_amdgcn_mfma_f32_16x16x32_bf16(zh1, bl1, cb, 0, 0, 0);
#pragma unroll
        for (int r = 0; r < 4; ++r)
            outb[(size_t)(orow0 + r) * F_ + h0] = ca[r] + cb[r];
    }
}

extern "C" void kernel_launch(void* const* d_in, const int* in_sizes, int n_in,
                              void* d_out, int out_size, void* d_ws, size_t ws_size,
                              hipStream_t stream) {
    (void)in_sizes; (void)n_in; (void)out_size; (void)ws_size;
    const float* x       = (const float*)d_in[0];
    const float* coeff   = (const float*)d_in[1];
    const float* gate    = (const float*)d_in[2];
    const float* coeff_l = (const float*)d_in[3];
    const float* gate_l  = (const float*)d_in[4];
    const float* comm    = (const float*)d_in[5];
    const float* l       = (const float*)d_in[6];
    const float* r       = (const float*)d_in[7];
    const float* ll      = (const float*)d_in[8];
    const float* rl      = (const float*)d_in[9];

    char* wsb = (char*)d_ws;
    float* GS = (float*)(wsb);                                // 4096 f      @0
    float* E  = (float*)(wsb + 16384);                        // 8*4096 f    @16K
    unsigned short* SEth = (unsigned short*)(wsb + 147456);   // 8*64*512    @144K
    unsigned short* SEtl = (unsigned short*)(wsb + 671744);   //             @656K
    unsigned short* Sbh  = (unsigned short*)(wsb + 1196032);  // 512*64      @1168K
    unsigned short* Sbl  = (unsigned short*)(wsb + 1261568);  //             @1232K
    float* out = (float*)d_out;

    k_prep<<<dim3(64), dim3(256), 0, stream>>>(l, r, ll, rl, GS, Sbh, Sbl);
    k_solve<<<dim3(8), dim3(256), 0, stream>>>(coeff, gate, coeff_l, gate_l, comm, GS, E);
    k_se<<<dim3(8, 8), dim3(256), 0, stream>>>(l, r, ll, rl, E, SEth, SEtl);
    k_mix<<<dim3(128, 8), dim3(256), 0, stream>>>(x, SEth, SEtl, Sbh, Sbl, out);
}

// Round 7
// 123.671 us; speedup vs baseline: 1.3205x; 1.2526x over previous
//
#include <hip/hip_runtime.h>

#define B_ 8
#define N_ 4096
#define F_ 512

typedef __attribute__((ext_vector_type(8))) short bf16x8;
typedef __attribute__((ext_vector_type(4))) float f32x4;

// S (512 x 64) = [left | right | left_local | right_local], each [512][16] row-major.
__device__ __forceinline__ float Sval(const float* l, const float* r,
                                      const float* ll, const float* rl,
                                      int h, int e) {
    const int m = e >> 4, c = e & 15;
    const float* p = (m == 0) ? l : (m == 1) ? r : (m == 2) ? ll : rl;
    return p[h * 16 + c];
}

__device__ __forceinline__ float qval(const float* coeff, const float* coeff_l,
                                      int b, int j) {
    if (j < 16) return 1.f;
    if (j < 32) return coeff[b * 16 + (j - 16)];
    if (j < 48) return 1.f;
    return coeff_l[b * 16 + (j - 48)];
}

__device__ __forceinline__ float lane_bcast(float v, int lane) {
    return __int_as_float(__builtin_amdgcn_readlane(__float_as_int(v), lane));
}

__device__ __forceinline__ unsigned short bf16_rn(float x) {
    unsigned u = __float_as_uint(x);
    unsigned r = u + 0x7FFFu + ((u >> 16) & 1u);
    return (unsigned short)(r >> 16);
}

// split x ~= hi + lo, both bf16 (error ~2^-17 |x|)
__device__ __forceinline__ void bf16_split(float x, short& hi, short& lo) {
    const unsigned short h = bf16_rn(x);
    const float hf = __uint_as_float(((unsigned)h) << 16);
    const unsigned short s = bf16_rn(x - hf);
    hi = (short)h; lo = (short)s;
}

// ---- k_prep: GS row i + S-fragment f2=i for phase-2 B-operand. grid 64.
// Sf layout (u16): [(f2*2 + hl)*512 + lane*8 + i], f2 = ht*2 + eh;
// value = S[h = ht*16 + (lane&15)][e = eh*32 + (lane>>4)*8 + i].
__global__ __launch_bounds__(256) void k_prep(const float* l, const float* r,
                                              const float* ll, const float* rl,
                                              float* GS, unsigned short* Sf) {
    __shared__ float red[4][64];
    const int i = blockIdx.x;
    const int t = threadIdx.x;
    const int j = t & 63, seg = t >> 6;

    // fragment f2 = i (coalesced 16B... 2x8B u16 writes per thread)
    {
        const int ht = i >> 1, eh = i & 1;
        for (int idx = t; idx < 512; idx += 256) {
            const int lx = idx >> 3, ii = idx & 7;
            const int h = ht * 16 + (lx & 15);
            const int e = eh * 32 + ((lx >> 4) & 3) * 8 + ii;
            short hh, ss;
            bf16_split(Sval(l, r, ll, rl, h, e), hh, ss);
            Sf[(i * 2 + 0) * 512 + idx] = (unsigned short)hh;
            Sf[(i * 2 + 1) * 512 + idx] = (unsigned short)ss;
        }
    }

    float acc = 0.f;
    const int h0 = seg * 128;
    for (int h = h0; h < h0 + 128; ++h)
        acc += Sval(l, r, ll, rl, h, i) * Sval(l, r, ll, rl, h, j);
    red[seg][j] = acc;
    __syncthreads();
    if (t < 64) GS[i * 64 + t] = red[0][t] + red[1][t] + red[2][t] + red[3][t];
}

// ---- macro-unrolled register Gauss-Jordan (literal indices only) ----
#define DO64(M, K) \
    M(0, K) M(1, K) M(2, K) M(3, K) M(4, K) M(5, K) M(6, K) M(7, K) \
    M(8, K) M(9, K) M(10, K) M(11, K) M(12, K) M(13, K) M(14, K) M(15, K) \
    M(16, K) M(17, K) M(18, K) M(19, K) M(20, K) M(21, K) M(22, K) M(23, K) \
    M(24, K) M(25, K) M(26, K) M(27, K) M(28, K) M(29, K) M(30, K) M(31, K) \
    M(32, K) M(33, K) M(34, K) M(35, K) M(36, K) M(37, K) M(38, K) M(39, K) \
    M(40, K) M(41, K) M(42, K) M(43, K) M(44, K) M(45, K) M(46, K) M(47, K) \
    M(48, K) M(49, K) M(50, K) M(51, K) M(52, K) M(53, K) M(54, K) M(55, K) \
    M(56, K) M(57, K) M(58, K) M(59, K) M(60, K) M(61, K) M(62, K) M(63, K)

#define GJ_LOAD(RR, K) a[RR] = MsL[(RR) * 64 + t];
#define GJ_STORE(RR, K) KsL[(RR) * 64 + t] = a[RR];
#define GJ_UPD(RR, K) \
    if ((RR) != (K)) { \
        const float f = lane_bcast(a[RR], (K)); \
        a[RR] = ((t == (K)) ? 0.f : a[RR]) - f * a[K]; \
    }
#define GJ_STEP(K) { \
    const float dk = lane_bcast(a[K], (K)); \
    const float pinv = 1.0f / dk; \
    a[K] = (t == (K)) ? pinv : a[K] * pinv; \
    DO64(GJ_UPD, K) \
}

// ---- k_solve: per-batch build M,CP -> wave-0 register GJ -> Newton -> E.
__global__ __launch_bounds__(256, 1) void k_solve(const float* coeff, const float* gate,
                                                  const float* coeff_l, const float* gate_l,
                                                  const float* comm, const float* GS,
                                                  float* Eout) {
    __shared__ float smem[16384];
    float* CPs = smem;
    float* GST = smem + 4096;
    float* MsL = smem + 8192;
    float* KsL = smem + 12288;
    float* ABs = MsL;       // dead before M written
    float* u1s = KsL;       // 32, dead before K written
    float* u2s = KsL + 32;  // 32

    const int b = blockIdx.x, t = threadIdx.x;
    const int tx = t & 15, ty = t >> 4;
    const float g = gate[b], gl = gate_l[b];
    const float cs = comm[b] / 12.0f;

    if (t < 32) {
        u1s[t] = (t < 16) ? g * coeff[b * 16 + t] : -g;
        u2s[t] = (t < 16) ? gl * coeff_l[b * 16 + t] : -gl;
    }
    for (int idx = t; idx < 4096; idx += 256) {
        const int i = idx & 63, e = idx >> 6;
        GST[idx] = -0.5f * qval(coeff, coeff_l, b, i) * GS[(i ^ 16) * 64 + e];
    }
    __syncthreads();

    for (int idx = t; idx < 2048; idx += 256) {
        const int which = idx >> 10;
        const int i = (idx >> 5) & 31, j = idx & 31;
        float val;
        if (which == 0) {
            const int v2i = (i < 16) ? 48 + i : 16 + i;
            const float v2sc = (i < 16) ? 1.f : coeff_l[b * 16 + (i - 16)];
            val = v2sc * u1s[j] * GS[v2i * 64 + j];
        } else {
            const int v1i = (i < 16) ? 16 + i : i - 16;
            const float v1sc = (i < 16) ? 1.f : coeff[b * 16 + (i - 16)];
            val = v1sc * u2s[j] * GS[v1i * 64 + 32 + j];
        }
        ABs[idx] = val;
    }
    __syncthreads();

    for (int idx = t; idx < 4096; idx += 256) {
        const int e = idx >> 6, j = idx & 63;
        float val = 0.f;
        if (j < 32) {
            if (e == j) val += 0.5f * u1s[j];
            if (e >= 32) val += cs * u2s[e - 32] * ABs[(e - 32) * 32 + j];
        } else {
            const int jp = j - 32;
            if (e == 32 + jp) val += 0.5f * u2s[jp];
            if (e < 32) val -= cs * u1s[e] * ABs[1024 + e * 32 + jp];
        }
        CPs[idx] = val;
    }
    __syncthreads();

    {
        const int i0 = ty * 4, m0 = tx * 4;
        float acc[4][4];
#pragma unroll
        for (int i = 0; i < 4; ++i)
#pragma unroll
            for (int j = 0; j < 4; ++j) acc[i][j] = 0.f;
        for (int e = 0; e < 64; ++e) {
            const float4 av = *reinterpret_cast<const float4*>(&GST[e * 64 + i0]);
            const float4 bv = *reinterpret_cast<const float4*>(&CPs[e * 64 + m0]);
            const float a[4] = {av.x, av.y, av.z, av.w};
            const float bb[4] = {bv.x, bv.y, bv.z, bv.w};
#pragma unroll
            for (int i = 0; i < 4; ++i)
#pragma unroll
                for (int j = 0; j < 4; ++j) acc[i][j] += a[i] * bb[j];
        }
        __syncthreads();
#pragma unroll
        for (int i = 0; i < 4; ++i)
#pragma unroll
            for (int j = 0; j < 4; ++j)
                MsL[(i0 + i) * 64 + m0 + j] =
                    acc[i][j] + (((i0 + i) == (m0 + j)) ? 1.f : 0.f);
    }
    __syncthreads();

    if (t < 64) {
        float a[64];
        DO64(GJ_LOAD, 0)
        GJ_STEP(0) GJ_STEP(1) GJ_STEP(2) GJ_STEP(3)
        GJ_STEP(4) GJ_STEP(5) GJ_STEP(6) GJ_STEP(7)
        GJ_STEP(8) GJ_STEP(9) GJ_STEP(10) GJ_STEP(11)
        GJ_STEP(12) GJ_STEP(13) GJ_STEP(14) GJ_STEP(15)
        GJ_STEP(16) GJ_STEP(17) GJ_STEP(18) GJ_STEP(19)
        GJ_STEP(20) GJ_STEP(21) GJ_STEP(22) GJ_STEP(23)
        GJ_STEP(24) GJ_STEP(25) GJ_STEP(26) GJ_STEP(27)
        GJ_STEP(28) GJ_STEP(29) GJ_STEP(30) GJ_STEP(31)
        GJ_STEP(32) GJ_STEP(33) GJ_STEP(34) GJ_STEP(35)
        GJ_STEP(36) GJ_STEP(37) GJ_STEP(38) GJ_STEP(39)
        GJ_STEP(40) GJ_STEP(41) GJ_STEP(42) GJ_STEP(43)
        GJ_STEP(44) GJ_STEP(45) GJ_STEP(46) GJ_STEP(47)
        GJ_STEP(48) GJ_STEP(49) GJ_STEP(50) GJ_STEP(51)
        GJ_STEP(52) GJ_STEP(53) GJ_STEP(54) GJ_STEP(55)
        GJ_STEP(56) GJ_STEP(57) GJ_STEP(58) GJ_STEP(59)
        GJ_STEP(60) GJ_STEP(61) GJ_STEP(62) GJ_STEP(63)
        DO64(GJ_STORE, 0)
    }
    __syncthreads();

    {
        const int i0 = ty * 4, j0 = tx * 4;
        float accd[4][4], acca[4][4];
#pragma unroll
        for (int i = 0; i < 4; ++i)
#pragma unroll
            for (int j = 0; j < 4; ++j) { accd[i][j] = 0.f; acca[i][j] = 0.f; }
        for (int q = 0; q < 64; ++q) {
            const float4 bv = *reinterpret_cast<const float4*>(&KsL[q * 64 + j0]);
            const float bb[4] = {bv.x, bv.y, bv.z, bv.w};
            float ad[4], aa[4];
#pragma unroll
            for (int i = 0; i < 4; ++i) {
                ad[i] = CPs[(i0 + i) * 64 + q];
                aa[i] = MsL[(i0 + i) * 64 + q];
            }
#pragma unroll
            for (int i = 0; i < 4; ++i)
#pragma unroll
                for (int j = 0; j < 4; ++j) {
                    accd[i][j] += ad[i] * bb[j];
                    acca[i][j] += aa[i] * bb[j];
                }
        }
        __syncthreads();
#pragma unroll
        for (int i = 0; i < 4; ++i)
#pragma unroll
            for (int j = 0; j < 4; ++j) {
                GST[(i0 + i) * 64 + j0 + j] = accd[i][j];  // Td
                CPs[(i0 + i) * 64 + j0 + j] = acca[i][j];  // Ta
            }
    }
    __syncthreads();

    {
        const int e0 = ty * 4, c0 = tx * 4;
        float acc[4][4];
#pragma unroll
        for (int i = 0; i < 4; ++i)
#pragma unroll
            for (int j = 0; j < 4; ++j) acc[i][j] = 0.f;
        for (int q = 0; q < 64; ++q) {
            const float4 bv = *reinterpret_cast<const float4*>(&CPs[q * 64 + c0]);
            const float bb[4] = {bv.x, bv.y, bv.z, bv.w};
            float a[4];
#pragma unroll
            for (int i = 0; i < 4; ++i) a[i] = GST[(e0 + i) * 64 + q];
#pragma unroll
            for (int i = 0; i < 4; ++i)
#pragma unroll
                for (int j = 0; j < 4; ++j) acc[i][j] += a[i] * bb[j];
        }
        float qv[4];
#pragma unroll
        for (int j = 0; j < 4; ++j) qv[j] = qval(coeff, coeff_l, b, c0 + j);
#pragma unroll
        for (int i = 0; i < 4; ++i) {
            float4 o;
            o.x = qv[0] * (2.f * GST[(e0 + i) * 64 + c0 + 0] - acc[i][0]);
            o.y = qv[1] * (2.f * GST[(e0 + i) * 64 + c0 + 1] - acc[i][1]);
            o.z = qv[2] * (2.f * GST[(e0 + i) * 64 + c0 + 2] - acc[i][2]);
            o.w = qv[3] * (2.f * GST[(e0 + i) * 64 + c0 + 3] - acc[i][3]);
            *reinterpret_cast<float4*>(&Eout[b * 4096 + (e0 + i) * 64 + (c0 ^ 16)]) = o;
        }
    }
}

// SE = S*E per batch, emitted in MFMA B-fragment layout (bf16 hi/lo):
// SEf (u16): [b*65536 + f*1024 + hl*512 + lane*8 + i], f = kk*4 + nt;
// value = SE[k = kk*32 + (lane>>4)*8 + i][n = nt*16 + (lane&15)].
// grid (hc=8, b=8): block covers h in [hc*64, hc*64+64) = fragments f in [8hc, 8hc+8).
__global__ __launch_bounds__(256) void k_se(const float* l, const float* r,
                                            const float* ll, const float* rl,
                                            const float* Ein, unsigned short* SEf) {
    __shared__ float Es[4096];
    __shared__ float Ss[64 * 66];
    __shared__ float SEs[64 * 65];
    const int b = blockIdx.y, hc = blockIdx.x, t = threadIdx.x;
    for (int idx = t; idx < 4096; idx += 256) {
        Es[idx] = Ein[b * 4096 + idx];
        const int hl_ = idx >> 6, e = idx & 63;
        Ss[hl_ * 66 + e] = Sval(l, r, ll, rl, hc * 64 + hl_, e);
    }
    __syncthreads();

    const int h = t >> 2;            // local row 0..63
    const int mg = (t & 3) * 16;
    float acc[16];
#pragma unroll
    for (int q = 0; q < 16; ++q) acc[q] = 0.f;
#pragma unroll 4
    for (int e = 0; e < 64; ++e) {
        const float s = Ss[h * 66 + e];
        const float* Er = Es + e * 64 + mg;
#pragma unroll
        for (int q = 0; q < 16; ++q) acc[q] += s * Er[q];
    }
#pragma unroll
    for (int q = 0; q < 16; ++q) SEs[h * 65 + mg + q] = acc[q];
    __syncthreads();

    // fragment-order bf16 writes, 16 B per thread per iter (fully coalesced)
    unsigned short* outp = SEf + (size_t)b * 65536 + hc * 8192;
#pragma unroll
    for (int it = 0; it < 4; ++it) {
        const int widx0 = it * 2048 + t * 8;
        const int fl = widx0 >> 10;            // 0..7
        const int hl = (widx0 >> 9) & 1;
        const int lx = (widx0 >> 3) & 63;
        const int m = (fl & 3) * 16 + (lx & 15);
        const int hb = (fl >> 2) * 32 + ((lx >> 4) & 3) * 8;
        unsigned short wv[8];
#pragma unroll
        for (int i = 0; i < 8; ++i) {
            short hh, ss;
            bf16_split(SEs[(hb + i) * 65 + m], hh, ss);
            wv[i] = hl ? (unsigned short)ss : (unsigned short)hh;
        }
        uint4 pk;
        pk.x = (unsigned)wv[0] | ((unsigned)wv[1] << 16);
        pk.y = (unsigned)wv[2] | ((unsigned)wv[3] << 16);
        pk.z = (unsigned)wv[4] | ((unsigned)wv[5] << 16);
        pk.w = (unsigned)wv[6] | ((unsigned)wv[7] << 16);
        *reinterpret_cast<uint4*>(outp + widx0) = pk;
    }
}

// out = x + ((x * SE_b) * S^T) via split-bf16 MFMA, fragment-major B operands.
// grid (row-tile=32 -> 128, b=8) = 1024 blocks, 256 thr = 4 waves.
// wave w: rw=w&1 (16-row half), cw=w>>1 (col half).
__global__ __launch_bounds__(256, 4) void k_mix(const float* x,
                                                const unsigned short* SEf,
                                                const unsigned short* Sf,
                                                float* out) {
    __shared__ float Zs[32 * 68];
    const int b = blockIdx.y;
    const int r0 = blockIdx.x * 32;
    const int t = threadIdx.x;
    const int w = t >> 6;
    const int l = t & 63;
    const int lm = l & 15;
    const int lk = (l >> 4) * 8;
    const int rw = w & 1, cw = w >> 1;
    const float* xb = x + (size_t)b * N_ * F_;
    float* outb = out + (size_t)b * N_ * F_;
    const unsigned short* sef = SEf + (size_t)b * 65536;

    // ---- phase 1: Z[32][64] = X_tile * SE ----
    f32x4 ahh0 = {0.f, 0.f, 0.f, 0.f}, alh0 = ahh0, ahl0 = ahh0;
    f32x4 ahh1 = ahh0, alh1 = ahh0, ahl1 = ahh0;
    const int arow = r0 + 16 * rw + lm;
    const float* xrow = xb + (size_t)arow * F_;
#pragma unroll 2
    for (int kk = 0; kk < 16; ++kk) {
        const int k0 = kk * 32 + lk;
        const float4 xa = *reinterpret_cast<const float4*>(xrow + k0);
        const float4 xc = *reinterpret_cast<const float4*>(xrow + k0 + 4);
        const float xs[8] = {xa.x, xa.y, xa.z, xa.w, xc.x, xc.y, xc.z, xc.w};
        bf16x8 ah, al;
#pragma unroll
        for (int i = 0; i < 8; ++i) {
            short hh, ss;
            bf16_split(xs[i], hh, ss);
            ah[i] = hh; al[i] = ss;
        }
        const int o0 = (kk * 4 + 2 * cw) * 1024 + l * 8;
        const bf16x8 bh0 = *reinterpret_cast<const bf16x8*>(sef + o0);
        const bf16x8 bl0 = *reinterpret_cast<const bf16x8*>(sef + o0 + 512);
        const bf16x8 bh1 = *reinterpret_cast<const bf16x8*>(sef + o0 + 1024);
        const bf16x8 bl1 = *reinterpret_cast<const bf16x8*>(sef + o0 + 1536);
        ahh0 = __builtin_amdgcn_mfma_f32_16x16x32_bf16(ah, bh0, ahh0, 0, 0, 0);
        alh0 = __builtin_amdgcn_mfma_f32_16x16x32_bf16(al, bh0, alh0, 0, 0, 0);
        ahl0 = __builtin_amdgcn_mfma_f32_16x16x32_bf16(ah, bl0, ahl0, 0, 0, 0);
        ahh1 = __builtin_amdgcn_mfma_f32_16x16x32_bf16(ah, bh1, ahh1, 0, 0, 0);
        alh1 = __builtin_amdgcn_mfma_f32_16x16x32_bf16(al, bh1, alh1, 0, 0, 0);
        ahl1 = __builtin_amdgcn_mfma_f32_16x16x32_bf16(ah, bl1, ahl1, 0, 0, 0);
    }
#pragma unroll
    for (int r = 0; r < 4; ++r) {
        const int zr = (16 * rw + (l >> 4) * 4 + r) * 68 + 32 * cw;
        Zs[zr + lm] = ahh0[r] + alh0[r] + ahl0[r];
        Zs[zr + 16 + lm] = ahh1[r] + alh1[r] + ahl1[r];
    }
    __syncthreads();

    // ---- phase 2: out[32][512] = X + Z * S^T ----
    bf16x8 zh0, zl0, zh1, zl1;
    {
        const float* zrow = &Zs[(16 * rw + lm) * 68];
#pragma unroll
        for (int i = 0; i < 8; ++i) {
            short hh, ss;
            bf16_split(zrow[lk + i], hh, ss);
            zh0[i] = hh; zl0[i] = ss;
            bf16_split(zrow[32 + lk + i], hh, ss);
            zh1[i] = hh; zl1[i] = ss;
        }
    }
    const int orow0 = r0 + 16 * rw + (l >> 4) * 4;
#pragma unroll 2
    for (int j2 = 0; j2 < 16; ++j2) {
        const int ht = cw * 16 + j2;
        const int h0 = ht * 16 + lm;
        f32x4 ca = {0.f, 0.f, 0.f, 0.f};
        f32x4 cb;
#pragma unroll
        for (int r = 0; r < 4; ++r) cb[r] = xb[(size_t)(orow0 + r) * F_ + h0];
        const int fb = ht * 2048 + l * 8;
        const bf16x8 bh0 = *reinterpret_cast<const bf16x8*>(Sf + fb);
        const bf16x8 bl0 = *reinterpret_cast<const bf16x8*>(Sf + fb + 512);
        const bf16x8 bh1 = *reinterpret_cast<const bf16x8*>(Sf + fb + 1024);
        const bf16x8 bl1 = *reinterpret_cast<const bf16x8*>(Sf + fb + 1536);
        ca = __builtin_amdgcn_mfma_f32_16x16x32_bf16(zh0, bh0, ca, 0, 0, 0);
        ca = __builtin_amdgcn_mfma_f32_16x16x32_bf16(zl0, bh0, ca, 0, 0, 0);
        ca = __builtin_amdgcn_mfma_f32_16x16x32_bf16(zh0, bl0, ca, 0, 0, 0);
        cb = __builtin_amdgcn_mfma_f32_16x16x32_bf16(zh1, bh1, cb, 0, 0, 0);
        cb = __builtin_amdgcn_mfma_f32_16x16x32_bf16(zl1, bh1, cb, 0, 0, 0);
        cb = __builtin_amdgcn_mfma_f32_16x16x32_bf16(zh1, bl1, cb, 0, 0, 0);
#pragma unroll
        for (int r = 0; r < 4; ++r)
            outb[(size_t)(orow0 + r) * F_ + h0] = ca[r] + cb[r];
    }
}

extern "C" void kernel_launch(void* const* d_in, const int* in_sizes, int n_in,
                              void* d_out, int out_size, void* d_ws, size_t ws_size,
                              hipStream_t stream) {
    (void)in_sizes; (void)n_in; (void)out_size; (void)ws_size;
    const float* x       = (const float*)d_in[0];
    const float* coeff   = (const float*)d_in[1];
    const float* gate    = (const float*)d_in[2];
    const float* coeff_l = (const float*)d_in[3];
    const float* gate_l  = (const float*)d_in[4];
    const float* comm    = (const float*)d_in[5];
    const float* l       = (const float*)d_in[6];
    const float* r       = (const float*)d_in[7];
    const float* ll      = (const float*)d_in[8];
    const float* rl      = (const float*)d_in[9];

    char* wsb = (char*)d_ws;
    float* GS = (float*)(wsb);                                // 4096 f       @0
    float* E  = (float*)(wsb + 16384);                        // 8*4096 f     @16K
    unsigned short* SEf = (unsigned short*)(wsb + 147456);    // 8*65536 u16  @144K (1MB)
    unsigned short* Sf  = (unsigned short*)(wsb + 1196032);   // 65536 u16    @1168K (128K)
    float* out = (float*)d_out;

    k_prep<<<dim3(64), dim3(256), 0, stream>>>(l, r, ll, rl, GS, Sf);
    k_solve<<<dim3(8), dim3(256), 0, stream>>>(coeff, gate, coeff_l, gate_l, comm, GS, E);
    k_se<<<dim3(8, 8), dim3(256), 0, stream>>>(l, r, ll, rl, E, SEf);
    k_mix<<<dim3(128, 8), dim3(256), 0, stream>>>(x, SEf, Sf, out);
}